// Round 1
// baseline (56978.522 us; speedup 1.0000x reference)
//
#include <hip/hip_runtime.h>
#include <cstddef>
#include <cstdint>
#include <math.h>

// ============================ constants ============================
static constexpr int NN   = 1024;   // lr_dim
static constexpr int HRD  = 2048;   // hr_dim
static constexpr int DIMF = 320;

#define EPI_NONE      0
#define EPI_BIAS      1
#define EPI_BIAS_ADD  2
#define EPI_ABS_DIAG1 3
#define EPI_RELU      4

// ============================ fp32 GEMM ============================
// C[M,N] = A[M,K] @ op(B), op(B)=B[K,N] or (TRB) B[N,K]^T, + epilogue
template<int EPI, bool TRB>
__global__ __launch_bounds__(256) void gemm32(
    const float* __restrict__ A, const float* __restrict__ B, float* __restrict__ C,
    int M, int N, int K, const float* __restrict__ bias, const float* __restrict__ D)
{
    __shared__ float As[16][65];
    __shared__ float Bs[16][65];
    const int bm = blockIdx.y << 6, bn = blockIdx.x << 6;
    const int tid = threadIdx.x;
    const int tm = (tid >> 4) << 2, tn = (tid & 15) << 2;
    float acc[4][4] = {};
    const int kt = (K + 15) >> 4;
    for (int k0 = 0; k0 < kt; ++k0){
        const int kb = k0 << 4;
        for (int t = tid; t < 1024; t += 256){
            int m = t >> 4, k = t & 15;
            int gm = bm + m, gk = kb + k;
            As[k][m] = (gm < M && gk < K) ? A[(size_t)gm*K + gk] : 0.f;
        }
        if (!TRB){
            for (int t = tid; t < 1024; t += 256){
                int k = t >> 6, nn2 = t & 63;
                int gk = kb + k, gn = bn + nn2;
                Bs[k][nn2] = (gk < K && gn < N) ? B[(size_t)gk*N + gn] : 0.f;
            }
        } else {
            for (int t = tid; t < 1024; t += 256){
                int nn2 = t >> 4, k = t & 15;
                int gk = kb + k, gn = bn + nn2;
                Bs[k][nn2] = (gk < K && gn < N) ? B[(size_t)gn*K + gk] : 0.f;
            }
        }
        __syncthreads();
        #pragma unroll
        for (int k = 0; k < 16; ++k){
            float a0 = As[k][tm], a1 = As[k][tm+1], a2 = As[k][tm+2], a3 = As[k][tm+3];
            float b0 = Bs[k][tn], b1 = Bs[k][tn+1], b2 = Bs[k][tn+2], b3 = Bs[k][tn+3];
            acc[0][0] += a0*b0; acc[0][1] += a0*b1; acc[0][2] += a0*b2; acc[0][3] += a0*b3;
            acc[1][0] += a1*b0; acc[1][1] += a1*b1; acc[1][2] += a1*b2; acc[1][3] += a1*b3;
            acc[2][0] += a2*b0; acc[2][1] += a2*b1; acc[2][2] += a2*b2; acc[2][3] += a2*b3;
            acc[3][0] += a3*b0; acc[3][1] += a3*b1; acc[3][2] += a3*b2; acc[3][3] += a3*b3;
        }
        __syncthreads();
    }
    #pragma unroll
    for (int r = 0; r < 4; ++r){
        int gm = bm + tm + r; if (gm >= M) continue;
        #pragma unroll
        for (int c = 0; c < 4; ++c){
            int gn = bn + tn + c; if (gn >= N) continue;
            float v = acc[r][c];
            if (EPI == EPI_BIAS)            v += bias[gn];
            else if (EPI == EPI_BIAS_ADD)   v += bias[gn] + D[(size_t)gm*N + gn];
            else if (EPI == EPI_ABS_DIAG1)  v = (gm == gn) ? 1.0f : fabsf(v);
            else if (EPI == EPI_RELU)       v = fmaxf(v, 0.0f);
            C[(size_t)gm*N + gn] = v;
        }
    }
}

// ============================ fp64 GEMM (back-transform) ============================
template<bool TRA>
__global__ __launch_bounds__(256) void gemm64k(
    const double* __restrict__ A, int lda, const double* __restrict__ B, int ldb,
    double* __restrict__ C, int ldc, int M, int N, int K, double alpha, double beta)
{
    __shared__ double As[16][33];
    __shared__ double Bs[16][33];
    const int bm = blockIdx.y << 5, bn = blockIdx.x << 5;
    const int tid = threadIdx.x;
    const int tm = (tid >> 4) << 1, tn = (tid & 15) << 1;
    double acc[2][2] = {};
    for (int kb = 0; kb < K; kb += 16){
        for (int t = tid; t < 512; t += 256){
            int m = t >> 4, k = t & 15;
            int gm = bm + m, gk = kb + k;
            double v = 0.0;
            if (gm < M && gk < K) v = TRA ? A[(size_t)gk*lda + gm] : A[(size_t)gm*lda + gk];
            As[k][m] = v;
        }
        for (int t = tid; t < 512; t += 256){
            int k = t >> 5, nn2 = t & 31;
            int gk = kb + k, gn = bn + nn2;
            Bs[k][nn2] = (gk < K && gn < N) ? B[(size_t)gk*ldb + gn] : 0.0;
        }
        __syncthreads();
        #pragma unroll
        for (int k = 0; k < 16; ++k){
            double a0 = As[k][tm], a1 = As[k][tm+1];
            double b0 = Bs[k][tn], b1 = Bs[k][tn+1];
            acc[0][0] += a0*b0; acc[0][1] += a0*b1;
            acc[1][0] += a1*b0; acc[1][1] += a1*b1;
        }
        __syncthreads();
    }
    #pragma unroll
    for (int r = 0; r < 2; ++r){
        int gm = bm + tm + r; if (gm >= M) continue;
        #pragma unroll
        for (int c = 0; c < 2; ++c){
            int gn = bn + tn + c; if (gn >= N) continue;
            double v = alpha*acc[r][c];
            if (beta != 0.0) v += beta*C[(size_t)gm*ldc + gn];
            C[(size_t)gm*ldc + gn] = v;
        }
    }
}

// ============================ small kernels ============================
__global__ __launch_bounds__(256) void rowsum_rsqrt_k(const float* __restrict__ lr, double* __restrict__ r64, int n)
{
    __shared__ double sm[256];
    int row = blockIdx.x;
    double s = 0.0;
    for (int j = threadIdx.x; j < n; j += 256) s += (double)lr[(size_t)row*n + j];
    sm[threadIdx.x] = s; __syncthreads();
    for (int o = 128; o; o >>= 1){ if (threadIdx.x < o) sm[threadIdx.x] += sm[threadIdx.x + o]; __syncthreads(); }
    if (threadIdx.x == 0){
        double t = sm[0];
        r64[row] = (t > 0.0) ? 1.0/sqrt(t) : 0.0;
    }
}

__global__ __launch_bounds__(256) void build_A_k(const float* __restrict__ lr, const double* __restrict__ r64,
                                                 float* __restrict__ A32, double* __restrict__ A64, int n)
{
    size_t idx = (size_t)blockIdx.x*256 + threadIdx.x;
    if (idx >= (size_t)n*n) return;
    int i = (int)(idx / n), j = (int)(idx % n);
    if (j < i) return;
    double v = (double)lr[(size_t)j*n + i] * r64[i] * r64[j];
    A64[(size_t)i*n + j] = v; A64[(size_t)j*n + i] = v;
    float vf = (float)v;
    A32[(size_t)i*n + j] = vf; A32[(size_t)j*n + i] = vf;
}

__global__ __launch_bounds__(256) void score_k(const float* __restrict__ X, const float* __restrict__ pw,
                                               const float* __restrict__ pb, float* __restrict__ out,
                                               int n, int dim)
{
    int row = blockIdx.x*4 + (threadIdx.x >> 6);
    int lane = threadIdx.x & 63;
    if (row >= n) return;
    float acc = 0.f;
    for (int c = lane; c < dim; c += 64) acc += X[(size_t)row*dim + c]*pw[c];
    #pragma unroll
    for (int o = 32; o; o >>= 1) acc += __shfl_down(acc, o);
    if (lane == 0){
        float t = (acc + pb[0]) * 0.01f;
        out[row] = 1.0f/(1.0f + expf(-t));
    }
}

// jax.lax.top_k semantics: descending value, ties -> lower index first
__global__ __launch_bounds__(256) void topk_k(const float* __restrict__ scores, int n, int k,
                                              int* __restrict__ idxo, float* __restrict__ valo)
{
    __shared__ float s[1024];
    int tid = threadIdx.x;
    for (int i = tid; i < n; i += 256) s[i] = scores[i];
    __syncthreads();
    for (int i = tid; i < n; i += 256){
        float si = s[i]; int r = 0;
        for (int j = 0; j < n; ++j){
            float sj = s[j];
            r += (sj > si) || (sj == si && j < i);
        }
        if (r < k){ idxo[r] = i; valo[r] = si; }
    }
}

__global__ __launch_bounds__(256) void gatherX_k(const float* __restrict__ X, const int* __restrict__ idx,
                                                 const float* __restrict__ vals, float* __restrict__ Xo,
                                                 int k, int dim)
{
    size_t t = (size_t)blockIdx.x*256 + threadIdx.x;
    if (t >= (size_t)k*dim) return;
    int m = (int)(t / dim), c = (int)(t % dim);
    Xo[t] = X[(size_t)idx[m]*dim + c] * vals[m];
}

__global__ __launch_bounds__(256) void scatterX_k(const float* __restrict__ Xs, const int* __restrict__ idx,
                                                  float* __restrict__ Xu, int k, int dim)
{
    size_t t = (size_t)blockIdx.x*256 + threadIdx.x;
    if (t >= (size_t)k*dim) return;
    int m = (int)(t / dim), c = (int)(t % dim);
    Xu[(size_t)idx[m]*dim + c] = Xs[t];
}

__global__ __launch_bounds__(256) void gatherA_k(const float* __restrict__ A, const int* __restrict__ idx,
                                                 float* __restrict__ Ao, int k, int n)
{
    size_t t = (size_t)blockIdx.x*256 + threadIdx.x;
    if (t >= (size_t)k*k) return;
    int m1 = (int)(t / k), m2 = (int)(t % k);
    Ao[t] = A[(size_t)idx[m1]*n + idx[m2]];
}

__global__ __launch_bounds__(256) void fill0_k(float* __restrict__ p, size_t cnt)
{
    size_t t = (size_t)blockIdx.x*256 + threadIdx.x;
    if (t < cnt) p[t] = 0.f;
}

__global__ __launch_bounds__(256) void concat_k(const float* __restrict__ X, const float* __restrict__ orgX,
                                                float* __restrict__ Xc, int n, int dim)
{
    size_t t = (size_t)blockIdx.x*256 + threadIdx.x;
    size_t tot = (size_t)n*2*dim;
    if (t >= tot) return;
    int i = (int)(t / (2*dim)), c = (int)(t % (2*dim));
    Xc[t] = (c < dim) ? X[(size_t)i*dim + c] : orgX[(size_t)i*dim + (c - dim)];
}

__global__ __launch_bounds__(256) void build_a_k(const float* __restrict__ gsr, float* __restrict__ a)
{
    size_t idx = (size_t)blockIdx.x*256 + threadIdx.x;
    if (idx >= (size_t)HRD*NN) return;
    int i = (int)(idx >> 10), k = (int)(idx & 1023);
    a[idx] = gsr[(size_t)i*HRD + k] + gsr[(size_t)i*HRD + NN + k];
}

__global__ __launch_bounds__(256) void symabs1_k(float* __restrict__ Z, int n)
{
    size_t idx = (size_t)blockIdx.x*256 + threadIdx.x;
    if (idx >= (size_t)n*n) return;
    int i = (int)(idx / n), j = (int)(idx % n);
    if (i > j) return;
    float a = Z[(size_t)i*n + j], b = Z[(size_t)j*n + i];
    float v = 0.5f*(a + b);
    float o = (i == j) ? 1.0f : fabsf(v);
    Z[(size_t)i*n + j] = o; Z[(size_t)j*n + i] = o;
}

__global__ __launch_bounds__(256) void final_z_k(const float* __restrict__ h2, float* __restrict__ z, int n)
{
    size_t idx = (size_t)blockIdx.x*256 + threadIdx.x;
    if (idx >= (size_t)n*n) return;
    int i = (int)(idx / n), j = (int)(idx % n);
    if (i > j) return;
    float v = 0.5f*(h2[(size_t)i*n + j] + h2[(size_t)j*n + i]);
    float o = (i == j) ? 1.0f : fabsf(v);
    z[(size_t)i*n + j] = o; z[(size_t)j*n + i] = o;
}

__global__ __launch_bounds__(256) void cast_d2f_k(const double* __restrict__ s, float* __restrict__ d, size_t cnt)
{
    size_t t = (size_t)blockIdx.x*256 + threadIdx.x;
    if (t < cnt) d[t] = (float)s[t];
}

// ============================ Householder tridiagonalization (fp64, 'L') ============================
__global__ __launch_bounds__(256) void hh_prepare(double* __restrict__ A64, double* __restrict__ e,
                                                  double* __restrict__ tau, double* __restrict__ vbuf,
                                                  double* __restrict__ pv, int n, int j)
{
    __shared__ double sm[256];
    __shared__ double s_scale;
    __shared__ int s_zero;
    int tid = threadIdx.x;
    double s = 0.0;
    for (int r2 = j+2+tid; r2 < n; r2 += 256){ double x = A64[(size_t)r2*n + j]; s += x*x; }
    sm[tid] = s; __syncthreads();
    for (int o = 128; o; o >>= 1){ if (tid < o) sm[tid] += sm[tid + o]; __syncthreads(); }
    if (tid == 0){
        pv[0] = 0.0;
        double sigma2 = sm[0];
        double alpha = A64[(size_t)(j+1)*n + j];
        if (sigma2 == 0.0){
            e[j] = alpha; tau[j] = 0.0; s_scale = 0.0; s_zero = 1;
        } else {
            double beta = -copysign(sqrt(alpha*alpha + sigma2), alpha);
            tau[j] = (beta - alpha)/beta;
            s_scale = 1.0/(alpha - beta);
            e[j] = beta; s_zero = 0;
        }
        vbuf[0] = 1.0;
        A64[(size_t)(j+1)*n + j] = 1.0;
    }
    __syncthreads();
    double sc = s_scale; int zz = s_zero;
    for (int r2 = j+2+tid; r2 < n; r2 += 256){
        double x = A64[(size_t)r2*n + j];
        double v = zz ? 0.0 : x*sc;
        A64[(size_t)r2*n + j] = v;
        vbuf[r2 - (j+1)] = v;
    }
}

__global__ __launch_bounds__(256) void hh_matvec(const double* __restrict__ A64, const double* __restrict__ vbuf,
                                                 double* __restrict__ p, double* __restrict__ pv, int n, int j)
{
    int m = n - 1 - j;
    int row = blockIdx.x*4 + (threadIdx.x >> 6);
    int lane = threadIdx.x & 63;
    if (row >= m) return;
    const double* Ar = A64 + (size_t)(j+1+row)*n + (j+1);
    double acc = 0.0;
    for (int c = lane; c < m; c += 64) acc += Ar[c]*vbuf[c];
    #pragma unroll
    for (int o = 32; o; o >>= 1) acc += __shfl_down(acc, o);
    if (lane == 0){ p[row] = acc; atomicAdd(pv, acc*vbuf[row]); }
}

__global__ __launch_bounds__(256) void hh_update(double* __restrict__ A64, const double* __restrict__ vbuf,
                                                 const double* __restrict__ p, const double* __restrict__ pv,
                                                 const double* __restrict__ tau, int n, int j)
{
    int m = n - 1 - j;
    size_t idx = (size_t)blockIdx.x*256 + threadIdx.x;
    size_t tot = (size_t)m*m;
    if (idx >= tot) return;
    int r = (int)(idx / m), c = (int)(idx % m);
    double t = tau[j];
    double c2 = 0.5*t*t*pv[0];
    double wr = t*p[r] - c2*vbuf[r];
    double wc = t*p[c] - c2*vbuf[c];
    A64[(size_t)(j+1+r)*n + (j+1+c)] -= vbuf[r]*wc + wr*vbuf[c];
}

__global__ __launch_bounds__(256) void extract_de_k(const double* __restrict__ A64, double* __restrict__ d,
                                                    double* __restrict__ e, int n)
{
    int i = blockIdx.x*256 + threadIdx.x;
    if (i < n) d[i] = A64[(size_t)i*n + i];
    if (i == 0) e[n-2] = A64[(size_t)(n-1)*n + (n-2)];
}

// ============================ tridiagonal eigensolver ============================
__global__ __launch_bounds__(256) void bisect_k(const double* __restrict__ d, const double* __restrict__ e,
                                                double* __restrict__ w, int n)
{
    int k = blockIdx.x*256 + threadIdx.x;
    if (k >= n) return;
    double gl = 1e300, gu = -1e300;
    for (int i = 0; i < n; ++i){
        double em = (i > 0) ? fabs(e[i-1]) : 0.0, ep = (i < n-1) ? fabs(e[i]) : 0.0;
        double lo2 = d[i] - em - ep, hi2 = d[i] + em + ep;
        gl = fmin(gl, lo2); gu = fmax(gu, hi2);
    }
    double lo = gl - 1e-10, hi = gu + 1e-10;
    const double pivmin = 1e-280;
    for (int it = 0; it < 64; ++it){
        double mid = 0.5*(lo + hi);
        int cnt = 0; double q = 1.0;
        for (int i = 0; i < n; ++i){
            double t;
            if (i == 0) t = d[0] - mid;
            else { double ei = e[i-1]; t = d[i] - mid - ei*(ei/q); }
            if (fabs(t) < pivmin) t = -pivmin;
            if (t < 0.0) ++cnt;
            q = t;
        }
        if (cnt <= k) lo = mid; else hi = mid;
    }
    w[k] = 0.5*(lo + hi);
}

__global__ __launch_bounds__(256) void invit_k(const double* __restrict__ d, const double* __restrict__ e,
                                               const double* __restrict__ w,
                                               double* __restrict__ FD, double* __restrict__ FL,
                                               double* __restrict__ FU, double* __restrict__ FU2,
                                               signed char* __restrict__ PIV, double* __restrict__ Z, int n)
{
    int k = blockIdx.x*256 + threadIdx.x;
    if (k >= n) return;
    double lam = w[k];
    const double tiny = 1e-280;
    for (int i = 0; i < n; ++i) FD[(size_t)i*n + k] = d[i] - lam;
    for (int i = 0; i < n-1; ++i){ FL[(size_t)i*n + k] = e[i]; FU[(size_t)i*n + k] = e[i]; }
    // pivoted LU (dgttrf-style)
    for (int i = 0; i < n-1; ++i){
        double di = FD[(size_t)i*n + k], dli = FL[(size_t)i*n + k];
        if (fabs(di) >= fabs(dli)){
            if (di == 0.0){ di = tiny; FD[(size_t)i*n + k] = di; }
            double f = dli/di;
            FL[(size_t)i*n + k] = f;
            FD[(size_t)(i+1)*n + k] -= f*FU[(size_t)i*n + k];
            if (i < n-2) FU2[(size_t)i*n + k] = 0.0;
            PIV[(size_t)i*n + k] = 0;
        } else {
            double f = di/dli;
            FD[(size_t)i*n + k] = dli; FL[(size_t)i*n + k] = f;
            double dnext = FD[(size_t)(i+1)*n + k];
            double dui = FU[(size_t)i*n + k];
            FU[(size_t)i*n + k] = dnext;
            FD[(size_t)(i+1)*n + k] = dui - f*dnext;
            if (i < n-2){
                double dun = FU[(size_t)(i+1)*n + k];
                FU2[(size_t)i*n + k] = dun;
                FU[(size_t)(i+1)*n + k] = -f*dun;
            }
            PIV[(size_t)i*n + k] = 1;
        }
    }
    if (FD[(size_t)(n-1)*n + k] == 0.0) FD[(size_t)(n-1)*n + k] = tiny;
    // pseudo-random start vector
    for (int i = 0; i < n; ++i){
        unsigned h = (unsigned)(i + 1)*0x9E3779B9u + (unsigned)(k + 1)*0x85EBCA6Bu;
        h ^= h >> 16; h *= 0x7FEB352Du; h ^= h >> 15; h *= 0x846CA68Bu; h ^= h >> 16;
        Z[(size_t)i*n + k] = (double)(h >> 8)*(1.0/16777216.0) - 0.5;
    }
    for (int iter = 0; iter < 2; ++iter){
        for (int i = 0; i < n-1; ++i){
            if (!PIV[(size_t)i*n + k]){
                Z[(size_t)(i+1)*n + k] -= FL[(size_t)i*n + k]*Z[(size_t)i*n + k];
            } else {
                double t = Z[(size_t)i*n + k] - FL[(size_t)i*n + k]*Z[(size_t)(i+1)*n + k];
                Z[(size_t)i*n + k] = Z[(size_t)(i+1)*n + k];
                Z[(size_t)(i+1)*n + k] = t;
            }
        }
        Z[(size_t)(n-1)*n + k] /= FD[(size_t)(n-1)*n + k];
        Z[(size_t)(n-2)*n + k] = (Z[(size_t)(n-2)*n + k] - FU[(size_t)(n-2)*n + k]*Z[(size_t)(n-1)*n + k]) / FD[(size_t)(n-2)*n + k];
        for (int i = n-3; i >= 0; --i)
            Z[(size_t)i*n + k] = (Z[(size_t)i*n + k] - FU[(size_t)i*n + k]*Z[(size_t)(i+1)*n + k]
                                  - FU2[(size_t)i*n + k]*Z[(size_t)(i+2)*n + k]) / FD[(size_t)i*n + k];
        double mx = 0.0;
        for (int i = 0; i < n; ++i) mx = fmax(mx, fabs(Z[(size_t)i*n + k]));
        double s = (mx > 0.0) ? 1.0/mx : 1.0;
        for (int i = 0; i < n; ++i) Z[(size_t)i*n + k] *= s;
    }
    double nrm = 0.0;
    for (int i = 0; i < n; ++i){ double v = Z[(size_t)i*n + k]; nrm += v*v; }
    double s = 1.0/sqrt(nrm);
    for (int i = 0; i < n; ++i) Z[(size_t)i*n + k] *= s;
}

// ============================ blocked-WY back-transform ============================
__global__ __launch_bounds__(256) void build_V_k(const double* __restrict__ A64, double* __restrict__ V,
                                                 int n, int b, int nbsz)
{
    size_t idx = (size_t)blockIdx.x*256 + threadIdx.x;
    if (idx >= (size_t)n*64) return;
    int r = (int)(idx >> 6), t = (int)(idx & 63);
    double v = 0.0;
    if (t < nbsz){ int j = b + t; if (r >= j + 1) v = A64[(size_t)r*n + j]; }
    V[(size_t)r*64 + t] = v;
}

// C = H(b) H(b+1) ... H(b+nbsz-1) = I - V T V^T, T upper triangular
__global__ __launch_bounds__(256) void build_T_k(const double* __restrict__ V, const double* __restrict__ tau,
                                                 double* __restrict__ T, int n, int b, int nbsz)
{
    __shared__ double G[64][64];
    int tid = threadIdx.x;
    for (int p = tid; p < 64*64; p += 256){
        int t = p >> 6, s2 = p & 63;
        double g = 0.0;
        if (t < s2 && s2 < nbsz){
            for (int r = b + s2 + 1; r < n; ++r) g += V[(size_t)r*64 + t]*V[(size_t)r*64 + s2];
        }
        G[t][s2] = g;
    }
    __syncthreads();
    for (int t = nbsz - 1; t >= 0; --t){
        for (int u = tid; u < nbsz; u += 256){
            if (u == t) T[t*64 + u] = tau[b + t];
            else if (u > t){
                double s = 0.0;
                for (int s2 = t + 1; s2 <= u; ++s2) s += G[t][s2]*T[s2*64 + u];
                T[t*64 + u] = -tau[b + t]*s;
            } else T[t*64 + u] = 0.0;
        }
        __syncthreads();
    }
}

// ============================ host dispatch helpers ============================
static void gemmf32(hipStream_t st, int epi, bool trb,
                    const float* A, const float* B, float* C, int M, int N, int K,
                    const float* bias, const float* D)
{
    dim3 g((N + 63)/64, (M + 63)/64), b(256);
    if (trb){
        gemm32<EPI_NONE, true><<<g, b, 0, st>>>(A, B, C, M, N, K, bias, D);
        return;
    }
    switch (epi){
    case EPI_NONE:      gemm32<EPI_NONE, false><<<g, b, 0, st>>>(A, B, C, M, N, K, bias, D); break;
    case EPI_BIAS:      gemm32<EPI_BIAS, false><<<g, b, 0, st>>>(A, B, C, M, N, K, bias, D); break;
    case EPI_BIAS_ADD:  gemm32<EPI_BIAS_ADD, false><<<g, b, 0, st>>>(A, B, C, M, N, K, bias, D); break;
    case EPI_ABS_DIAG1: gemm32<EPI_ABS_DIAG1, false><<<g, b, 0, st>>>(A, B, C, M, N, K, bias, D); break;
    case EPI_RELU:      gemm32<EPI_RELU, false><<<g, b, 0, st>>>(A, B, C, M, N, K, bias, D); break;
    }
}

static void gemmf64(hipStream_t st, bool tra,
                    const double* A, int lda, const double* B, int ldb,
                    double* C, int ldc, int M, int N, int K, double alpha, double beta)
{
    dim3 g((N + 31)/32, (M + 31)/32), b(256);
    if (tra) gemm64k<true ><<<g, b, 0, st>>>(A, lda, B, ldb, C, ldc, M, N, K, alpha, beta);
    else     gemm64k<false><<<g, b, 0, st>>>(A, lda, B, ldb, C, ldc, M, N, K, alpha, beta);
}

// ============================ kernel_launch ============================
extern "C" void kernel_launch(void* const* d_in, const int* in_sizes, int n_in,
                              void* d_out, int out_size, void* d_ws, size_t ws_size,
                              hipStream_t stream)
{
    (void)in_sizes; (void)n_in; (void)out_size; (void)ws_size;
    const float* lr       = (const float*)d_in[0];
    const float* gsr_w    = (const float*)d_in[1];
    const float* start_w  = (const float*)d_in[2];
    const float* start_b  = (const float*)d_in[3];
    const float* down_w   = (const float*)d_in[4];
    const float* down_b   = (const float*)d_in[5];
    const float* pool_w   = (const float*)d_in[6];
    const float* pool_b   = (const float*)d_in[7];
    const float* bottom_w = (const float*)d_in[8];
    const float* bottom_b = (const float*)d_in[9];
    const float* end_w    = (const float*)d_in[10];
    const float* end_b    = (const float*)d_in[11];
    const float* up_w     = (const float*)d_in[12];
    const float* up_b     = (const float*)d_in[13];
    const float* gc1      = (const float*)d_in[14];
    const float* gc2      = (const float*)d_in[15];

    float* out_z     = (float*)d_out;                       // [2048,2048]
    float* out_net   = out_z + (size_t)HRD*HRD;             // [1024,2048]
    float* out_start = out_net + (size_t)NN*HRD;            // [1024,320]
    float* out_adj   = out_start + (size_t)NN*DIMF;         // [2048,2048]

    static const int LVL_N[4] = {1024, 921, 644, 386};
    static const int LVL_K[4] = {921, 644, 386, 193};

    // -------- workspace arena (needs ~62 MB) --------
    char* Wb = (char*)d_ws;
    size_t off = 0;
    auto alloc = [&](size_t bb)->char*{ char* p = Wb + off; off = (off + bb + 255) & ~(size_t)255; return p; };

    float*  A32  = (float*) alloc((size_t)NN*NN*4);
    double* A64  = (double*)alloc((size_t)NN*NN*8);
    float*  Uf   = (float*) alloc((size_t)NN*NN*4);
    double* r64  = (double*)alloc(NN*8);
    double* dD   = (double*)alloc(NN*8);
    double* dE   = (double*)alloc(NN*8);
    double* dTau = (double*)alloc(NN*8);
    double* dWev = (double*)alloc(NN*8);
    double* pbuf = (double*)alloc(NN*8);
    double* vbuf = (double*)alloc(NN*8);
    double* pv   = (double*)alloc(256);
    double* Tm   = (double*)alloc(64*64*8);
    double* Vp   = (double*)alloc((size_t)NN*64*8);
    double* Yt   = (double*)alloc((size_t)64*NN*8);
    double* W2   = (double*)alloc((size_t)64*NN*8);
    char* SBASE = Wb + off;

    // P2 overlay (U-Net)
    size_t so = 0;
    auto salloc = [&](size_t bb)->char*{ char* p = SBASE + so; so = (so + bb + 255) & ~(size_t)255; return p; };
    float* XT  = (float*)salloc((size_t)NN*DIMF*4);
    float* XP1 = (float*)salloc((size_t)NN*DIMF*4);
    float* XP2 = (float*)salloc((size_t)NN*DIMF*4);
    float* XU  = (float*)salloc((size_t)NN*DIMF*4);
    float* DN[4]; for (int l = 0; l < 4; ++l) DN[l] = (float*)salloc((size_t)NN*DIMF*4);
    float* Asub[4];
    for (int l = 0; l < 4; ++l) Asub[l] = (float*)salloc((size_t)LVL_K[l]*LVL_K[l]*4);
    float* SC = (float*)salloc(NN*4);
    int*   IDX[4]; for (int l = 0; l < 4; ++l) IDX[l] = (int*)salloc(NN*4);
    float* VAL[4]; for (int l = 0; l < 4; ++l) VAL[l] = (float*)salloc(NN*4);
    float* XC  = (float*)salloc((size_t)NN*2*DIMF*4);
    float* AXC = (float*)salloc((size_t)NN*2*DIMF*4);

    // P3 overlay (eigensolver scratch)
    const size_t PL = (size_t)NN*NN*8;
    double* Z64 = (double*)(SBASE);
    double* FD  = (double*)(SBASE + PL);
    double* FL  = (double*)(SBASE + 2*PL);
    double* FU  = (double*)(SBASE + 3*PL);
    double* FU2 = (double*)(SBASE + 4*PL);
    signed char* FPIV = (signed char*)(SBASE + 5*PL);

    // P4 overlay (GSR / refinement)
    float* P4a  = (float*)(SBASE);
    float* P4t1 = (float*)(SBASE + (size_t)HRD*NN*4);
    float* P4Zb = (float*)(SBASE);
    float* P4ZG = (float*)(SBASE + (size_t)HRD*HRD*4);
    float* P4h1 = (float*)(SBASE + (size_t)HRD*HRD*4 + (size_t)HRD*NN*4);
    float* P4HG = (float*)(SBASE);
    float* P4h2 = (float*)(SBASE + (size_t)HRD*HRD*4);

    // =============== P1: normalized adjacency ===============
    rowsum_rsqrt_k<<<NN, 256, 0, stream>>>(lr, r64, NN);
    build_A_k<<<(NN*NN + 255)/256, 256, 0, stream>>>(lr, r64, A32, A64, NN);

    // =============== P2: graph U-Net (fp32) ===============
    // start gcn: (A @ I) @ W + b = A @ W + b  -> start_outs (directly to d_out)
    gemmf32(stream, EPI_BIAS, false, A32, start_w, out_start, NN, DIMF, NN, start_b, nullptr);

    const float* Xcur = out_start;
    const float* Acur = A32;
    float* ping = XP1; float* pong = XP2;
    for (int l = 0; l < 4; ++l){
        int nl = LVL_N[l], kl = LVL_K[l];
        gemmf32(stream, EPI_NONE, false, Acur, Xcur, XT, nl, DIMF, nl, nullptr, nullptr);
        gemmf32(stream, EPI_BIAS, false, XT, down_w + (size_t)l*DIMF*DIMF, DN[l], nl, DIMF, DIMF,
                down_b + (size_t)l*DIMF, nullptr);
        score_k<<<(nl + 3)/4, 256, 0, stream>>>(DN[l], pool_w + (size_t)l*DIMF, pool_b + l, SC, nl, DIMF);
        topk_k<<<1, 256, 0, stream>>>(SC, nl, kl, IDX[l], VAL[l]);
        gatherX_k<<<(unsigned)(((size_t)kl*DIMF + 255)/256), 256, 0, stream>>>(DN[l], IDX[l], VAL[l], ping, kl, DIMF);
        gatherA_k<<<(unsigned)(((size_t)kl*kl + 255)/256), 256, 0, stream>>>(Acur, IDX[l], Asub[l], kl, nl);
        Xcur = ping; Acur = Asub[l];
        float* t = ping; ping = pong; pong = t;
    }
    // bottom gcn (193)
    gemmf32(stream, EPI_NONE, false, Acur, Xcur, XT, 193, DIMF, 193, nullptr, nullptr);
    float* Xb = ping;
    gemmf32(stream, EPI_BIAS, false, XT, bottom_w, Xb, 193, DIMF, DIMF, bottom_b, nullptr);
    // up path
    const float* Xup = Xb;
    float* upbuf[2] = { (Xb == XP1) ? XP2 : XP1, (Xb == XP1) ? XP1 : XP2 };
    for (int i2 = 0; i2 < 4; ++i2){
        int jl = 3 - i2;
        int nj = LVL_N[jl];
        int kj = LVL_K[jl];
        fill0_k<<<(unsigned)(((size_t)nj*DIMF + 255)/256), 256, 0, stream>>>(XU, (size_t)nj*DIMF);
        scatterX_k<<<(unsigned)(((size_t)kj*DIMF + 255)/256), 256, 0, stream>>>(Xup, IDX[jl], XU, kj, DIMF);
        const float* Aj = (jl == 0) ? A32 : Asub[jl - 1];
        gemmf32(stream, EPI_NONE, false, Aj, XU, XT, nj, DIMF, nj, nullptr, nullptr);
        float* Xn = upbuf[i2 & 1];
        gemmf32(stream, EPI_BIAS_ADD, false, XT, up_w + (size_t)i2*DIMF*DIMF, Xn, nj, DIMF, DIMF,
                up_b + (size_t)i2*DIMF, DN[jl]);
        Xup = Xn;
    }
    concat_k<<<(unsigned)(((size_t)NN*2*DIMF + 255)/256), 256, 0, stream>>>(Xup, out_start, XC, NN, DIMF);
    gemmf32(stream, EPI_NONE, false, A32, XC, AXC, NN, 2*DIMF, NN, nullptr, nullptr);
    gemmf32(stream, EPI_BIAS, false, AXC, end_w, out_net, NN, HRD, 2*DIMF, end_b, nullptr);

    // =============== P3: eigendecomposition of A (fp64) ===============
    for (int j = 0; j <= NN - 3; ++j){
        int m = NN - 1 - j;
        hh_prepare<<<1, 256, 0, stream>>>(A64, dE, dTau, vbuf, pv, NN, j);
        hh_matvec<<<(m + 3)/4, 256, 0, stream>>>(A64, vbuf, pbuf, pv, NN, j);
        size_t tot = (size_t)m*m;
        hh_update<<<(unsigned)((tot + 255)/256), 256, 0, stream>>>(A64, vbuf, pbuf, pv, dTau, NN, j);
    }
    extract_de_k<<<4, 256, 0, stream>>>(A64, dD, dE, NN);
    bisect_k<<<4, 256, 0, stream>>>(dD, dE, dWev, NN);
    invit_k<<<4, 256, 0, stream>>>(dD, dE, dWev, FD, FL, FU, FU2, FPIV, Z64, NN);
    // back-transform U = H0 H1 ... H(n-3) Z, blocked WY, groups descending
    for (int g = 15; g >= 0; --g){
        int b0 = g*64;
        int nbsz = (NN - 2) - b0; if (nbsz > 64) nbsz = 64;
        build_V_k<<<(NN*64 + 255)/256, 256, 0, stream>>>(A64, Vp, NN, b0, nbsz);
        build_T_k<<<1, 256, 0, stream>>>(Vp, dTau, Tm, NN, b0, nbsz);
        int r0 = b0 + 1;
        gemmf64(stream, true,  Vp + (size_t)r0*64, 64, Z64 + (size_t)r0*NN, NN, Yt, NN, nbsz, NN, NN - r0, 1.0, 0.0);
        gemmf64(stream, false, Tm, 64, Yt, NN, W2, NN, nbsz, NN, nbsz, 1.0, 0.0);
        gemmf64(stream, false, Vp + (size_t)r0*64, 64, W2, NN, Z64 + (size_t)r0*NN, NN, NN - r0, NN, nbsz, -1.0, 1.0);
    }
    cast_d2f_k<<<(unsigned)(((size_t)NN*NN + 255)/256), 256, 0, stream>>>(Z64, Uf, (size_t)NN*NN);

    // =============== P4: GSR layer + refinement (fp32) ===============
    build_a_k<<<(unsigned)(((size_t)HRD*NN + 255)/256), 256, 0, stream>>>(gsr_w, P4a);
    gemmf32(stream, EPI_NONE, true,  P4a, Uf, P4t1, HRD, NN, NN, nullptr, nullptr);          // a @ U^T
    gemmf32(stream, EPI_ABS_DIAG1, false, P4t1, out_net, out_adj, HRD, HRD, NN, nullptr, nullptr); // adj
    gemmf32(stream, EPI_NONE, true,  out_adj, out_adj, P4Zb, HRD, HRD, HRD, nullptr, nullptr); // adj adj^T
    symabs1_k<<<(unsigned)(((size_t)HRD*HRD + 255)/256), 256, 0, stream>>>(P4Zb, HRD);        // Z
    gemmf32(stream, EPI_NONE, false, P4Zb, gc1, P4ZG, HRD, NN, HRD, nullptr, nullptr);        // Z @ gc1
    gemmf32(stream, EPI_RELU, false, out_adj, P4ZG, P4h1, HRD, NN, HRD, nullptr, nullptr);    // h1
    gemmf32(stream, EPI_NONE, false, P4h1, gc2, P4HG, HRD, HRD, NN, nullptr, nullptr);        // h1 @ gc2
    gemmf32(stream, EPI_RELU, false, out_adj, P4HG, P4h2, HRD, HRD, HRD, nullptr, nullptr);   // h2
    final_z_k<<<(unsigned)(((size_t)HRD*HRD + 255)/256), 256, 0, stream>>>(P4h2, out_z, HRD); // z
}

// Round 2
// 54410.168 us; speedup vs baseline: 1.0472x; 1.0472x over previous
//
#include <hip/hip_runtime.h>
#include <cstddef>
#include <cstdint>
#include <math.h>

// ============================ constants ============================
static constexpr int NN   = 1024;   // lr_dim
static constexpr int HRD  = 2048;   // hr_dim
static constexpr int DIMF = 320;
static constexpr int TB   = 85;     // sytrd LDS tail block (85x87 fp64 = 59 KB LDS)

#define EPI_NONE      0
#define EPI_BIAS      1
#define EPI_BIAS_ADD  2
#define EPI_ABS_DIAG1 3
#define EPI_RELU      4

// ============================ fp32 GEMM 64-tile (fallback, odd K) ============================
template<int EPI>
__global__ __launch_bounds__(256) void gemm32(
    const float* __restrict__ A, const float* __restrict__ B, float* __restrict__ C,
    int M, int N, int K, const float* __restrict__ bias, const float* __restrict__ D)
{
    __shared__ float As[16][65];
    __shared__ float Bs[16][65];
    const int bm = blockIdx.y << 6, bn = blockIdx.x << 6;
    const int tid = threadIdx.x;
    const int tm = (tid >> 4) << 2, tn = (tid & 15) << 2;
    float acc[4][4] = {};
    const int kt = (K + 15) >> 4;
    for (int k0 = 0; k0 < kt; ++k0){
        const int kb = k0 << 4;
        for (int t = tid; t < 1024; t += 256){
            int m = t >> 4, k = t & 15;
            int gm = bm + m, gk = kb + k;
            As[k][m] = (gm < M && gk < K) ? A[(size_t)gm*K + gk] : 0.f;
        }
        for (int t = tid; t < 1024; t += 256){
            int k = t >> 6, nn2 = t & 63;
            int gk = kb + k, gn = bn + nn2;
            Bs[k][nn2] = (gk < K && gn < N) ? B[(size_t)gk*N + gn] : 0.f;
        }
        __syncthreads();
        #pragma unroll
        for (int k = 0; k < 16; ++k){
            float a0 = As[k][tm], a1 = As[k][tm+1], a2 = As[k][tm+2], a3 = As[k][tm+3];
            float b0 = Bs[k][tn], b1 = Bs[k][tn+1], b2 = Bs[k][tn+2], b3 = Bs[k][tn+3];
            acc[0][0] += a0*b0; acc[0][1] += a0*b1; acc[0][2] += a0*b2; acc[0][3] += a0*b3;
            acc[1][0] += a1*b0; acc[1][1] += a1*b1; acc[1][2] += a1*b2; acc[1][3] += a1*b3;
            acc[2][0] += a2*b0; acc[2][1] += a2*b1; acc[2][2] += a2*b2; acc[2][3] += a2*b3;
            acc[3][0] += a3*b0; acc[3][1] += a3*b1; acc[3][2] += a3*b2; acc[3][3] += a3*b3;
        }
        __syncthreads();
    }
    #pragma unroll
    for (int r = 0; r < 4; ++r){
        int gm = bm + tm + r; if (gm >= M) continue;
        #pragma unroll
        for (int c = 0; c < 4; ++c){
            int gn = bn + tn + c; if (gn >= N) continue;
            float v = acc[r][c];
            if (EPI == EPI_BIAS)            v += bias[gn];
            else if (EPI == EPI_BIAS_ADD)   v += bias[gn] + D[(size_t)gm*N + gn];
            else if (EPI == EPI_ABS_DIAG1)  v = (gm == gn) ? 1.0f : fabsf(v);
            else if (EPI == EPI_RELU)       v = fmaxf(v, 0.0f);
            C[(size_t)gm*N + gn] = v;
        }
    }
}

// ============================ fp32 GEMM 128-tile (K%16==0, N%8==0) ============================
template<int EPI>
__global__ __launch_bounds__(256) void gemm128(
    const float* __restrict__ A, const float* __restrict__ B, float* __restrict__ C,
    int M, int N, int K, const float* __restrict__ bias, const float* __restrict__ D)
{
    __shared__ float As[16][132];
    __shared__ float Bs[16][132];
    const int bm = blockIdx.y << 7, bn = blockIdx.x << 7;
    const int tid = threadIdx.x;
    const int tm = (tid >> 4) << 3;
    const int tn = (tid & 15) << 3;
    const int ar = tid >> 1;          // A-load row 0..127
    const int ak = (tid & 1) << 3;    // A-load k offset 0/8
    const int br = tid >> 4;          // B-load k-row 0..15
    const int bc = (tid & 15) << 3;   // B-load col offset
    float acc[8][8] = {};
    for (int kb = 0; kb < K; kb += 16){
        {   // A tile -> transposed LDS store
            int gm = bm + ar, gk = kb + ak;
            float4 a0, a1;
            if (gm < M){
                const float* p = A + (size_t)gm*K + gk;
                a0 = *(const float4*)p; a1 = *(const float4*)(p + 4);
            } else { a0 = make_float4(0.f,0.f,0.f,0.f); a1 = a0; }
            As[ak+0][ar]=a0.x; As[ak+1][ar]=a0.y; As[ak+2][ar]=a0.z; As[ak+3][ar]=a0.w;
            As[ak+4][ar]=a1.x; As[ak+5][ar]=a1.y; As[ak+6][ar]=a1.z; As[ak+7][ar]=a1.w;
        }
        {   // B tile
            int gk = kb + br, gn = bn + bc;
            float4 b0, b1;
            if (gn + 7 < N){
                const float* p = B + (size_t)gk*N + gn;
                b0 = *(const float4*)p; b1 = *(const float4*)(p + 4);
            } else {
                float t0[8];
                #pragma unroll
                for (int i = 0; i < 8; ++i){ int g = gn + i; t0[i] = (g < N) ? B[(size_t)gk*N + g] : 0.f; }
                b0 = make_float4(t0[0],t0[1],t0[2],t0[3]); b1 = make_float4(t0[4],t0[5],t0[6],t0[7]);
            }
            *(float4*)&Bs[br][bc] = b0; *(float4*)&Bs[br][bc+4] = b1;
        }
        __syncthreads();
        #pragma unroll
        for (int k = 0; k < 16; ++k){
            float4 a0 = *(const float4*)&As[k][tm];
            float4 a1 = *(const float4*)&As[k][tm+4];
            float4 b0 = *(const float4*)&Bs[k][tn];
            float4 b1 = *(const float4*)&Bs[k][tn+4];
            float av[8] = {a0.x,a0.y,a0.z,a0.w,a1.x,a1.y,a1.z,a1.w};
            float bv[8] = {b0.x,b0.y,b0.z,b0.w,b1.x,b1.y,b1.z,b1.w};
            #pragma unroll
            for (int i = 0; i < 8; ++i)
                #pragma unroll
                for (int jj = 0; jj < 8; ++jj) acc[i][jj] += av[i]*bv[jj];
        }
        __syncthreads();
    }
    #pragma unroll
    for (int i = 0; i < 8; ++i){
        int gm = bm + tm + i; if (gm >= M) continue;
        #pragma unroll
        for (int jj = 0; jj < 8; ++jj){
            int gn = bn + tn + jj; if (gn >= N) continue;
            float v = acc[i][jj];
            if (EPI == EPI_BIAS)            v += bias[gn];
            else if (EPI == EPI_BIAS_ADD)   v += bias[gn] + D[(size_t)gm*N + gn];
            else if (EPI == EPI_ABS_DIAG1)  v = (gm == gn) ? 1.0f : fabsf(v);
            else if (EPI == EPI_RELU)       v = fmaxf(v, 0.0f);
            C[(size_t)gm*N + gn] = v;
        }
    }
}

// ============================ fp64 GEMM (back-transform) ============================
template<bool TRA>
__global__ __launch_bounds__(256) void gemm64k(
    const double* __restrict__ A, int lda, const double* __restrict__ B, int ldb,
    double* __restrict__ C, int ldc, int M, int N, int K, double alpha, double beta)
{
    __shared__ double As[16][33];
    __shared__ double Bs[16][33];
    const int bm = blockIdx.y << 5, bn = blockIdx.x << 5;
    const int tid = threadIdx.x;
    const int tm = (tid >> 4) << 1, tn = (tid & 15) << 1;
    double acc[2][2] = {};
    for (int kb = 0; kb < K; kb += 16){
        for (int t = tid; t < 512; t += 256){
            int m = t >> 4, k = t & 15;
            int gm = bm + m, gk = kb + k;
            double v = 0.0;
            if (gm < M && gk < K) v = TRA ? A[(size_t)gk*lda + gm] : A[(size_t)gm*lda + gk];
            As[k][m] = v;
        }
        for (int t = tid; t < 512; t += 256){
            int k = t >> 5, nn2 = t & 31;
            int gk = kb + k, gn = bn + nn2;
            Bs[k][nn2] = (gk < K && gn < N) ? B[(size_t)gk*ldb + gn] : 0.0;
        }
        __syncthreads();
        #pragma unroll
        for (int k = 0; k < 16; ++k){
            double a0 = As[k][tm], a1 = As[k][tm+1];
            double b0 = Bs[k][tn], b1 = Bs[k][tn+1];
            acc[0][0] += a0*b0; acc[0][1] += a0*b1;
            acc[1][0] += a1*b0; acc[1][1] += a1*b1;
        }
        __syncthreads();
    }
    #pragma unroll
    for (int r = 0; r < 2; ++r){
        int gm = bm + tm + r; if (gm >= M) continue;
        #pragma unroll
        for (int c = 0; c < 2; ++c){
            int gn = bn + tn + c; if (gn >= N) continue;
            double v = alpha*acc[r][c];
            if (beta != 0.0) v += beta*C[(size_t)gm*ldc + gn];
            C[(size_t)gm*ldc + gn] = v;
        }
    }
}

// ============================ small kernels ============================
__global__ __launch_bounds__(256) void rowsum_rsqrt_k(const float* __restrict__ lr, double* __restrict__ r64, int n)
{
    __shared__ double sm[256];
    int row = blockIdx.x;
    double s = 0.0;
    for (int j = threadIdx.x; j < n; j += 256) s += (double)lr[(size_t)row*n + j];
    sm[threadIdx.x] = s; __syncthreads();
    for (int o = 128; o; o >>= 1){ if (threadIdx.x < o) sm[threadIdx.x] += sm[threadIdx.x + o]; __syncthreads(); }
    if (threadIdx.x == 0){
        double t = sm[0];
        r64[row] = (t > 0.0) ? 1.0/sqrt(t) : 0.0;
    }
}

__global__ __launch_bounds__(256) void build_A_k(const float* __restrict__ lr, const double* __restrict__ r64,
                                                 float* __restrict__ A32, double* __restrict__ A64, int n)
{
    size_t idx = (size_t)blockIdx.x*256 + threadIdx.x;
    if (idx >= (size_t)n*n) return;
    int i = (int)(idx / n), j = (int)(idx % n);
    if (j < i) return;
    double v = (double)lr[(size_t)j*n + i] * r64[i] * r64[j];
    A64[(size_t)i*n + j] = v; A64[(size_t)j*n + i] = v;
    float vf = (float)v;
    A32[(size_t)i*n + j] = vf; A32[(size_t)j*n + i] = vf;
}

__global__ __launch_bounds__(256) void score_k(const float* __restrict__ X, const float* __restrict__ pw,
                                               const float* __restrict__ pb, float* __restrict__ out,
                                               int n, int dim)
{
    int row = blockIdx.x*4 + (threadIdx.x >> 6);
    int lane = threadIdx.x & 63;
    if (row >= n) return;
    float acc = 0.f;
    for (int c = lane; c < dim; c += 64) acc += X[(size_t)row*dim + c]*pw[c];
    #pragma unroll
    for (int o = 32; o; o >>= 1) acc += __shfl_down(acc, o);
    if (lane == 0){
        float t = (acc + pb[0]) * 0.01f;
        out[row] = 1.0f/(1.0f + expf(-t));
    }
}

// jax.lax.top_k semantics: descending value, ties -> lower index first
__global__ __launch_bounds__(256) void topk_k(const float* __restrict__ scores, int n, int k,
                                              int* __restrict__ idxo, float* __restrict__ valo)
{
    __shared__ float s[1024];
    int tid = threadIdx.x;
    for (int i = tid; i < n; i += 256) s[i] = scores[i];
    __syncthreads();
    for (int i = tid; i < n; i += 256){
        float si = s[i]; int r = 0;
        for (int j = 0; j < n; ++j){
            float sj = s[j];
            r += (sj > si) || (sj == si && j < i);
        }
        if (r < k){ idxo[r] = i; valo[r] = si; }
    }
}

__global__ __launch_bounds__(256) void gatherX_k(const float* __restrict__ X, const int* __restrict__ idx,
                                                 const float* __restrict__ vals, float* __restrict__ Xo,
                                                 int k, int dim)
{
    size_t t = (size_t)blockIdx.x*256 + threadIdx.x;
    if (t >= (size_t)k*dim) return;
    int m = (int)(t / dim), c = (int)(t % dim);
    Xo[t] = X[(size_t)idx[m]*dim + c] * vals[m];
}

__global__ __launch_bounds__(256) void scatterX_k(const float* __restrict__ Xs, const int* __restrict__ idx,
                                                  float* __restrict__ Xu, int k, int dim)
{
    size_t t = (size_t)blockIdx.x*256 + threadIdx.x;
    if (t >= (size_t)k*dim) return;
    int m = (int)(t / dim), c = (int)(t % dim);
    Xu[(size_t)idx[m]*dim + c] = Xs[t];
}

__global__ __launch_bounds__(256) void gatherA_k(const float* __restrict__ A, const int* __restrict__ idx,
                                                 float* __restrict__ Ao, int k, int n)
{
    size_t t = (size_t)blockIdx.x*256 + threadIdx.x;
    if (t >= (size_t)k*k) return;
    int m1 = (int)(t / k), m2 = (int)(t % k);
    Ao[t] = A[(size_t)idx[m1]*n + idx[m2]];
}

__global__ __launch_bounds__(256) void fill0_k(float* __restrict__ p, size_t cnt)
{
    size_t t = (size_t)blockIdx.x*256 + threadIdx.x;
    if (t < cnt) p[t] = 0.f;
}

__global__ __launch_bounds__(256) void filld0_k(double* __restrict__ p, int cnt)
{
    int t = blockIdx.x*256 + threadIdx.x;
    if (t < cnt) p[t] = 0.0;
}

__global__ __launch_bounds__(256) void concat_k(const float* __restrict__ X, const float* __restrict__ orgX,
                                                float* __restrict__ Xc, int n, int dim)
{
    size_t t = (size_t)blockIdx.x*256 + threadIdx.x;
    size_t tot = (size_t)n*2*dim;
    if (t >= tot) return;
    int i = (int)(t / (2*dim)), c = (int)(t % (2*dim));
    Xc[t] = (c < dim) ? X[(size_t)i*dim + c] : orgX[(size_t)i*dim + (c - dim)];
}

__global__ __launch_bounds__(256) void build_a_k(const float* __restrict__ gsr, float* __restrict__ a)
{
    size_t idx = (size_t)blockIdx.x*256 + threadIdx.x;
    if (idx >= (size_t)HRD*NN) return;
    int i = (int)(idx >> 10), k = (int)(idx & 1023);
    a[idx] = gsr[(size_t)i*HRD + k] + gsr[(size_t)i*HRD + NN + k];
}

__global__ __launch_bounds__(256) void symabs1_k(float* __restrict__ Z, int n)
{
    size_t idx = (size_t)blockIdx.x*256 + threadIdx.x;
    if (idx >= (size_t)n*n) return;
    int i = (int)(idx / n), j = (int)(idx % n);
    if (i > j) return;
    float a = Z[(size_t)i*n + j], b = Z[(size_t)j*n + i];
    float v = 0.5f*(a + b);
    float o = (i == j) ? 1.0f : fabsf(v);
    Z[(size_t)i*n + j] = o; Z[(size_t)j*n + i] = o;
}

__global__ __launch_bounds__(256) void final_z_k(const float* __restrict__ h2, float* __restrict__ z, int n)
{
    size_t idx = (size_t)blockIdx.x*256 + threadIdx.x;
    if (idx >= (size_t)n*n) return;
    int i = (int)(idx / n), j = (int)(idx % n);
    if (i > j) return;
    float v = 0.5f*(h2[(size_t)i*n + j] + h2[(size_t)j*n + i]);
    float o = (i == j) ? 1.0f : fabsf(v);
    z[(size_t)i*n + j] = o; z[(size_t)j*n + i] = o;
}

// dst[c][r] = (float)src[r][c]   (n x n, n % 32 == 0)
__global__ __launch_bounds__(256) void transpose_cast_k(const double* __restrict__ src, float* __restrict__ dst, int n)
{
    __shared__ float tile[32][33];
    int r0 = blockIdx.y*32, c0 = blockIdx.x*32;
    int tx = threadIdx.x & 31, ty = threadIdx.x >> 5;
    for (int i = ty; i < 32; i += 8)
        tile[i][tx] = (float)src[(size_t)(r0 + i)*n + (c0 + tx)];
    __syncthreads();
    for (int i = ty; i < 32; i += 8)
        dst[(size_t)(c0 + i)*n + (r0 + tx)] = tile[tx][i];
}

// dst[c][r] = src[r][c]  (n x n, n % 32 == 0)
__global__ __launch_bounds__(256) void transpose32_k(const float* __restrict__ src, float* __restrict__ dst, int n)
{
    __shared__ float tile[32][33];
    int r0 = blockIdx.y*32, c0 = blockIdx.x*32;
    int tx = threadIdx.x & 31, ty = threadIdx.x >> 5;
    for (int i = ty; i < 32; i += 8)
        tile[i][tx] = src[(size_t)(r0 + i)*n + (c0 + tx)];
    __syncthreads();
    for (int i = ty; i < 32; i += 8)
        dst[(size_t)(c0 + i)*n + (r0 + tx)] = tile[tx][i];
}

// ============================ Householder tridiagonalization (fp64) ============================
// v lives implicitly in ROW j of A64 (symmetric matrix): v[0]=1, v[c]=row[c]*scale.
// Fused: per-block redundant norm/tau/scale recompute (bitwise identical), then matvec p = A_tr * v.
__global__ __launch_bounds__(256) void hh_fused_mv(double* __restrict__ A64, double* __restrict__ e,
                                                   double* __restrict__ tau, double* __restrict__ scaleg,
                                                   double* __restrict__ p, double* __restrict__ pv,
                                                   int n, int j)
{
    __shared__ double red[256];
    __shared__ double sh_scale;
    const int m = n - 1 - j;
    const int tid = threadIdx.x;
    const double* __restrict__ row = A64 + (size_t)j*n + (j+1);  // row[0]=alpha, row[1..m-1]=tail
    double s = 0.0;
    for (int c = 1 + tid; c < m; c += 256){ double x = row[c]; s += x*x; }
    red[tid] = s; __syncthreads();
    for (int o = 128; o; o >>= 1){ if (tid < o) red[tid] += red[tid + o]; __syncthreads(); }
    if (tid == 0){
        double sigma2 = red[0], alpha = row[0];
        double beta, tl, sc;
        if (sigma2 == 0.0){ beta = alpha; tl = 0.0; sc = 0.0; }
        else {
            beta = -copysign(sqrt(alpha*alpha + sigma2), alpha);
            tl = (beta - alpha)/beta;
            sc = 1.0/(alpha - beta);
        }
        sh_scale = sc;
        if (blockIdx.x == 0){ e[j] = beta; tau[j] = tl; scaleg[j] = sc; }
    }
    __syncthreads();
    double sc = sh_scale;
    int rrow = blockIdx.x*4 + (tid >> 6);
    int lane = tid & 63;
    if (rrow >= m) return;
    const double* __restrict__ Ar = A64 + (size_t)(j+1+rrow)*n + (j+1);
    double acc = 0.0;
    for (int c = lane; c < m; c += 64){
        double vv = (c == 0) ? 1.0 : row[c]*sc;
        acc += Ar[c]*vv;
    }
    #pragma unroll
    for (int o = 32; o; o >>= 1) acc += __shfl_down(acc, o);
    if (lane == 0){
        double vr = (rrow == 0) ? 1.0 : row[rrow]*sc;
        p[rrow] = acc;
        atomicAdd(&pv[j], acc*vr);
    }
}

__global__ __launch_bounds__(256) void hh_update2(double* __restrict__ A64, const double* __restrict__ p,
                                                  const double* __restrict__ pv, const double* __restrict__ tau,
                                                  const double* __restrict__ scaleg, int n, int j)
{
    const int m = n - 1 - j;
    size_t idx = (size_t)blockIdx.x*256 + threadIdx.x;
    size_t tot = (size_t)m*m;
    if (idx >= tot) return;
    int r = (int)(idx / m), c = (int)(idx % m);
    double t = tau[j], sc = scaleg[j];
    const double* __restrict__ row = A64 + (size_t)j*n + (j+1);
    double c2 = 0.5*t*t*pv[j];
    double vr = (r == 0) ? 1.0 : row[r]*sc;
    double vc = (c == 0) ? 1.0 : row[c]*sc;
    double wr = t*p[r] - c2*vr;
    double wc = t*p[c] - c2*vc;
    A64[(size_t)(j+1+r)*n + (j+1+c)] -= vr*wc + wr*vc;
}

// Tail: remaining (TB-2) Householder steps entirely in LDS (single block).
__global__ __launch_bounds__(256) void hh_tail(double* __restrict__ A64, double* __restrict__ e,
                                               double* __restrict__ tau, double* __restrict__ scaleg, int n)
{
    __shared__ double T[TB][TB+2];
    __shared__ double v[TB], p[TB], red[256];
    const int base = n - TB;
    const int tid = threadIdx.x;
    for (int t = tid; t < TB*TB; t += 256){
        int r = t / TB, c = t % TB;
        T[r][c] = A64[(size_t)(base + r)*n + base + c];
    }
    __syncthreads();
    for (int l = 0; l <= TB - 3; ++l){
        const int m = TB - 1 - l;
        // sigma2 over column l tail (rows l+2..)
        double s = 0.0;
        for (int i = 1 + tid; i < m; i += 256){ double x = T[l+1+i][l]; s += x*x; }
        red[tid] = s; __syncthreads();
        for (int o = 128; o; o >>= 1){ if (tid < o) red[tid] += red[tid + o]; __syncthreads(); }
        double sigma2 = red[0];
        double alpha = T[l+1][l];
        double beta, tl, sc;
        if (sigma2 == 0.0){ beta = alpha; tl = 0.0; sc = 0.0; }
        else {
            beta = -copysign(sqrt(alpha*alpha + sigma2), alpha);
            tl = (beta - alpha)/beta;
            sc = 1.0/(alpha - beta);
        }
        for (int i = tid; i < m; i += 256) v[i] = (i == 0) ? 1.0 : T[l+1+i][l]*sc;
        __syncthreads();
        // p = T_trailing * v
        for (int i = tid; i < m; i += 256){
            double acc = 0.0;
            for (int c = 0; c < m; ++c) acc += T[l+1+i][l+1+c]*v[c];
            p[i] = acc;
        }
        __syncthreads();
        double s2 = 0.0;
        for (int i = tid; i < m; i += 256) s2 += p[i]*v[i];
        red[tid] = s2; __syncthreads();
        for (int o = 128; o; o >>= 1){ if (tid < o) red[tid] += red[tid + o]; __syncthreads(); }
        double pvv = red[0];
        double c2 = 0.5*tl*tl*pvv;
        for (int t2 = tid; t2 < m*m; t2 += 256){
            int r = t2 / m, c = t2 % m;
            double wr = tl*p[r] - c2*v[r];
            double wc = tl*p[c] - c2*v[c];
            T[l+1+r][l+1+c] -= v[r]*wc + wr*v[c];
        }
        if (tid == 0){ int j = base + l; e[j] = beta; tau[j] = tl; scaleg[j] = 1.0; }
        // store v (incl leading 1) into global row base+l for the back-transform
        for (int i = tid; i < m; i += 256) A64[(size_t)(base + l)*n + (base + l + 1) + i] = v[i];
        __syncthreads();
    }
    // write back diag (d values) and the final subdiagonal e[n-2]
    for (int r = tid; r < TB; r += 256) A64[(size_t)(base + r)*n + base + r] = T[r][r];
    if (tid == 0) A64[(size_t)(n-1)*n + (n-2)] = T[TB-1][TB-2];
}

__global__ __launch_bounds__(256) void extract_de_k(const double* __restrict__ A64, double* __restrict__ d,
                                                    double* __restrict__ e, int n)
{
    int i = blockIdx.x*256 + threadIdx.x;
    if (i < n) d[i] = A64[(size_t)i*n + i];
    if (i == 0) e[n-2] = A64[(size_t)(n-1)*n + (n-2)];
}

// ============================ tridiagonal eigensolver ============================
__global__ __launch_bounds__(256) void bisect_k(const double* __restrict__ d, const double* __restrict__ e,
                                                double* __restrict__ w, int n)
{
    int k = blockIdx.x*256 + threadIdx.x;
    if (k >= n) return;
    double gl = 1e300, gu = -1e300;
    for (int i = 0; i < n; ++i){
        double em = (i > 0) ? fabs(e[i-1]) : 0.0, ep = (i < n-1) ? fabs(e[i]) : 0.0;
        double lo2 = d[i] - em - ep, hi2 = d[i] + em + ep;
        gl = fmin(gl, lo2); gu = fmax(gu, hi2);
    }
    double lo = gl - 1e-10, hi = gu + 1e-10;
    const double pivmin = 1e-280;
    for (int it = 0; it < 50; ++it){
        double mid = 0.5*(lo + hi);
        int cnt = 0; double q = 1.0;
        for (int i = 0; i < n; ++i){
            double t;
            if (i == 0) t = d[0] - mid;
            else { double ei = e[i-1]; t = d[i] - mid - ei*(ei/q); }
            if (fabs(t) < pivmin) t = -pivmin;
            if (t < 0.0) ++cnt;
            q = t;
        }
        if (cnt <= k) lo = mid; else hi = mid;
    }
    w[k] = 0.5*(lo + hi);
}

__global__ __launch_bounds__(256) void invit_k(const double* __restrict__ d, const double* __restrict__ e,
                                               const double* __restrict__ w,
                                               double* __restrict__ FD, double* __restrict__ FL,
                                               double* __restrict__ FU, double* __restrict__ FU2,
                                               signed char* __restrict__ PIV, double* __restrict__ Z, int n)
{
    int k = blockIdx.x*256 + threadIdx.x;
    if (k >= n) return;
    double lam = w[k];
    const double tiny = 1e-280;
    for (int i = 0; i < n; ++i) FD[(size_t)i*n + k] = d[i] - lam;
    for (int i = 0; i < n-1; ++i){ FL[(size_t)i*n + k] = e[i]; FU[(size_t)i*n + k] = e[i]; }
    for (int i = 0; i < n-1; ++i){
        double di = FD[(size_t)i*n + k], dli = FL[(size_t)i*n + k];
        if (fabs(di) >= fabs(dli)){
            if (di == 0.0){ di = tiny; FD[(size_t)i*n + k] = di; }
            double f = dli/di;
            FL[(size_t)i*n + k] = f;
            FD[(size_t)(i+1)*n + k] -= f*FU[(size_t)i*n + k];
            if (i < n-2) FU2[(size_t)i*n + k] = 0.0;
            PIV[(size_t)i*n + k] = 0;
        } else {
            double f = di/dli;
            FD[(size_t)i*n + k] = dli; FL[(size_t)i*n + k] = f;
            double dnext = FD[(size_t)(i+1)*n + k];
            double dui = FU[(size_t)i*n + k];
            FU[(size_t)i*n + k] = dnext;
            FD[(size_t)(i+1)*n + k] = dui - f*dnext;
            if (i < n-2){
                double dun = FU[(size_t)(i+1)*n + k];
                FU2[(size_t)i*n + k] = dun;
                FU[(size_t)(i+1)*n + k] = -f*dun;
            }
            PIV[(size_t)i*n + k] = 1;
        }
    }
    if (FD[(size_t)(n-1)*n + k] == 0.0) FD[(size_t)(n-1)*n + k] = tiny;
    for (int i = 0; i < n; ++i){
        unsigned h = (unsigned)(i + 1)*0x9E3779B9u + (unsigned)(k + 1)*0x85EBCA6Bu;
        h ^= h >> 16; h *= 0x7FEB352Du; h ^= h >> 15; h *= 0x846CA68Bu; h ^= h >> 16;
        Z[(size_t)i*n + k] = (double)(h >> 8)*(1.0/16777216.0) - 0.5;
    }
    for (int iter = 0; iter < 2; ++iter){
        for (int i = 0; i < n-1; ++i){
            if (!PIV[(size_t)i*n + k]){
                Z[(size_t)(i+1)*n + k] -= FL[(size_t)i*n + k]*Z[(size_t)i*n + k];
            } else {
                double t = Z[(size_t)i*n + k] - FL[(size_t)i*n + k]*Z[(size_t)(i+1)*n + k];
                Z[(size_t)i*n + k] = Z[(size_t)(i+1)*n + k];
                Z[(size_t)(i+1)*n + k] = t;
            }
        }
        Z[(size_t)(n-1)*n + k] /= FD[(size_t)(n-1)*n + k];
        Z[(size_t)(n-2)*n + k] = (Z[(size_t)(n-2)*n + k] - FU[(size_t)(n-2)*n + k]*Z[(size_t)(n-1)*n + k]) / FD[(size_t)(n-2)*n + k];
        for (int i = n-3; i >= 0; --i)
            Z[(size_t)i*n + k] = (Z[(size_t)i*n + k] - FU[(size_t)i*n + k]*Z[(size_t)(i+1)*n + k]
                                  - FU2[(size_t)i*n + k]*Z[(size_t)(i+2)*n + k]) / FD[(size_t)i*n + k];
        double mx = 0.0;
        for (int i = 0; i < n; ++i) mx = fmax(mx, fabs(Z[(size_t)i*n + k]));
        double s = (mx > 0.0) ? 1.0/mx : 1.0;
        for (int i = 0; i < n; ++i) Z[(size_t)i*n + k] *= s;
    }
    double nrm = 0.0;
    for (int i = 0; i < n; ++i){ double v = Z[(size_t)i*n + k]; nrm += v*v; }
    double s = 1.0/sqrt(nrm);
    for (int i = 0; i < n; ++i) Z[(size_t)i*n + k] *= s;
}

// ============================ blocked-WY back-transform ============================
// v_j stored in ROW j of A64 (cols j+1..): v(r)=1 at r==j+1, else A64[j][r]*scale[j]
__global__ __launch_bounds__(256) void build_V_k(const double* __restrict__ A64, const double* __restrict__ scaleg,
                                                 double* __restrict__ V, int n, int b, int nbsz)
{
    size_t idx = (size_t)blockIdx.x*256 + threadIdx.x;
    if (idx >= (size_t)n*64) return;
    int r = (int)(idx >> 6), t = (int)(idx & 63);
    double v = 0.0;
    if (t < nbsz){
        int j = b + t;
        if (r == j + 1) v = 1.0;
        else if (r > j + 1) v = A64[(size_t)j*n + r]*scaleg[j];
    }
    V[(size_t)r*64 + t] = v;
}

__global__ __launch_bounds__(256) void build_T_k(const double* __restrict__ V, const double* __restrict__ tau,
                                                 double* __restrict__ T, int n, int b, int nbsz)
{
    __shared__ double G[64][64];
    int tid = threadIdx.x;
    for (int p = tid; p < 64*64; p += 256){
        int t = p >> 6, s2 = p & 63;
        double g = 0.0;
        if (t < s2 && s2 < nbsz){
            for (int r = b + s2 + 1; r < n; ++r) g += V[(size_t)r*64 + t]*V[(size_t)r*64 + s2];
        }
        G[t][s2] = g;
    }
    __syncthreads();
    for (int t = nbsz - 1; t >= 0; --t){
        for (int u = tid; u < nbsz; u += 256){
            if (u == t) T[t*64 + u] = tau[b + t];
            else if (u > t){
                double s = 0.0;
                for (int s2 = t + 1; s2 <= u; ++s2) s += G[t][s2]*T[s2*64 + u];
                T[t*64 + u] = -tau[b + t]*s;
            } else T[t*64 + u] = 0.0;
        }
        __syncthreads();
    }
}

// ============================ host dispatch helpers ============================
static void gemmf32(hipStream_t st, int epi,
                    const float* A, const float* B, float* C, int M, int N, int K,
                    const float* bias, const float* D)
{
    if ((K & 15) == 0 && (N & 7) == 0){
        dim3 g((N + 127)/128, (M + 127)/128), b(256);
        switch (epi){
        case EPI_NONE:      gemm128<EPI_NONE><<<g, b, 0, st>>>(A, B, C, M, N, K, bias, D); break;
        case EPI_BIAS:      gemm128<EPI_BIAS><<<g, b, 0, st>>>(A, B, C, M, N, K, bias, D); break;
        case EPI_BIAS_ADD:  gemm128<EPI_BIAS_ADD><<<g, b, 0, st>>>(A, B, C, M, N, K, bias, D); break;
        case EPI_ABS_DIAG1: gemm128<EPI_ABS_DIAG1><<<g, b, 0, st>>>(A, B, C, M, N, K, bias, D); break;
        case EPI_RELU:      gemm128<EPI_RELU><<<g, b, 0, st>>>(A, B, C, M, N, K, bias, D); break;
        }
    } else {
        dim3 g((N + 63)/64, (M + 63)/64), b(256);
        switch (epi){
        case EPI_NONE:      gemm32<EPI_NONE><<<g, b, 0, st>>>(A, B, C, M, N, K, bias, D); break;
        case EPI_BIAS:      gemm32<EPI_BIAS><<<g, b, 0, st>>>(A, B, C, M, N, K, bias, D); break;
        case EPI_BIAS_ADD:  gemm32<EPI_BIAS_ADD><<<g, b, 0, st>>>(A, B, C, M, N, K, bias, D); break;
        case EPI_ABS_DIAG1: gemm32<EPI_ABS_DIAG1><<<g, b, 0, st>>>(A, B, C, M, N, K, bias, D); break;
        case EPI_RELU:      gemm32<EPI_RELU><<<g, b, 0, st>>>(A, B, C, M, N, K, bias, D); break;
        }
    }
}

static void gemmf64(hipStream_t st, bool tra,
                    const double* A, int lda, const double* B, int ldb,
                    double* C, int ldc, int M, int N, int K, double alpha, double beta)
{
    dim3 g((N + 31)/32, (M + 31)/32), b(256);
    if (tra) gemm64k<true ><<<g, b, 0, st>>>(A, lda, B, ldb, C, ldc, M, N, K, alpha, beta);
    else     gemm64k<false><<<g, b, 0, st>>>(A, lda, B, ldb, C, ldc, M, N, K, alpha, beta);
}

// ============================ kernel_launch ============================
extern "C" void kernel_launch(void* const* d_in, const int* in_sizes, int n_in,
                              void* d_out, int out_size, void* d_ws, size_t ws_size,
                              hipStream_t stream)
{
    (void)in_sizes; (void)n_in; (void)out_size; (void)ws_size;
    const float* lr       = (const float*)d_in[0];
    const float* gsr_w    = (const float*)d_in[1];
    const float* start_w  = (const float*)d_in[2];
    const float* start_b  = (const float*)d_in[3];
    const float* down_w   = (const float*)d_in[4];
    const float* down_b   = (const float*)d_in[5];
    const float* pool_w   = (const float*)d_in[6];
    const float* pool_b   = (const float*)d_in[7];
    const float* bottom_w = (const float*)d_in[8];
    const float* bottom_b = (const float*)d_in[9];
    const float* end_w    = (const float*)d_in[10];
    const float* end_b    = (const float*)d_in[11];
    const float* up_w     = (const float*)d_in[12];
    const float* up_b     = (const float*)d_in[13];
    const float* gc1      = (const float*)d_in[14];
    const float* gc2      = (const float*)d_in[15];

    float* out_z     = (float*)d_out;                       // [2048,2048]
    float* out_net   = out_z + (size_t)HRD*HRD;             // [1024,2048]
    float* out_start = out_net + (size_t)NN*HRD;            // [1024,320]
    float* out_adj   = out_start + (size_t)NN*DIMF;         // [2048,2048]

    static const int LVL_N[4] = {1024, 921, 644, 386};
    static const int LVL_K[4] = {921, 644, 386, 193};

    // -------- workspace arena --------
    char* Wb = (char*)d_ws;
    size_t off = 0;
    auto alloc = [&](size_t bb)->char*{ char* p = Wb + off; off = (off + bb + 255) & ~(size_t)255; return p; };

    float*  A32  = (float*) alloc((size_t)NN*NN*4);
    double* A64  = (double*)alloc((size_t)NN*NN*8);
    float*  UfT  = (float*) alloc((size_t)NN*NN*4);   // U^T as [k][j] fp32
    double* r64  = (double*)alloc(NN*8);
    double* dD   = (double*)alloc(NN*8);
    double* dE   = (double*)alloc(NN*8);
    double* dTau = (double*)alloc(NN*8);
    double* dScl = (double*)alloc(NN*8);
    double* dWev = (double*)alloc(NN*8);
    double* pbuf = (double*)alloc(NN*8);
    double* pvA  = (double*)alloc(NN*8);
    double* Tm   = (double*)alloc(64*64*8);
    double* Vp   = (double*)alloc((size_t)NN*64*8);
    double* Yt   = (double*)alloc((size_t)64*NN*8);
    double* W2   = (double*)alloc((size_t)64*NN*8);
    char* SBASE = Wb + off;

    // P2 overlay (U-Net)
    size_t so = 0;
    auto salloc = [&](size_t bb)->char*{ char* p = SBASE + so; so = (so + bb + 255) & ~(size_t)255; return p; };
    float* XT  = (float*)salloc((size_t)NN*DIMF*4);
    float* XP1 = (float*)salloc((size_t)NN*DIMF*4);
    float* XP2 = (float*)salloc((size_t)NN*DIMF*4);
    float* XU  = (float*)salloc((size_t)NN*DIMF*4);
    float* DN[4]; for (int l = 0; l < 4; ++l) DN[l] = (float*)salloc((size_t)NN*DIMF*4);
    float* Asub[4];
    for (int l = 0; l < 4; ++l) Asub[l] = (float*)salloc((size_t)LVL_K[l]*LVL_K[l]*4);
    float* SC = (float*)salloc(NN*4);
    int*   IDX[4]; for (int l = 0; l < 4; ++l) IDX[l] = (int*)salloc(NN*4);
    float* VAL[4]; for (int l = 0; l < 4; ++l) VAL[l] = (float*)salloc(NN*4);
    float* XC  = (float*)salloc((size_t)NN*2*DIMF*4);
    float* AXC = (float*)salloc((size_t)NN*2*DIMF*4);

    // P3 overlay (eigensolver scratch) — 41 MiB beyond SBASE
    const size_t PL = (size_t)NN*NN*8;
    double* Z64 = (double*)(SBASE);
    double* FD  = (double*)(SBASE + PL);
    double* FL  = (double*)(SBASE + 2*PL);
    double* FU  = (double*)(SBASE + 3*PL);
    double* FU2 = (double*)(SBASE + 4*PL);
    signed char* FPIV = (signed char*)(SBASE + 5*PL);

    // P4 overlay (GSR / refinement) — max extent 32 MiB beyond SBASE
    const size_t MB8  = (size_t)HRD*NN*4;    // 8 MiB
    const size_t MB16 = (size_t)HRD*HRD*4;   // 16 MiB
    float* P4a   = (float*)(SBASE);               // [2048,1024]
    float* P4t1  = (float*)(SBASE + MB8);         // [2048,1024]
    float* P4adT = (float*)(SBASE);               // [2048,2048]
    float* P4Zb  = (float*)(SBASE + MB16);        // [2048,2048]
    float* P4ZG  = (float*)(SBASE);               // [2048,1024]
    float* P4h1  = (float*)(SBASE + MB8);         // [2048,1024]
    float* P4HG  = (float*)(SBASE + MB16);        // [2048,2048]
    float* P4h2  = (float*)(SBASE);               // [2048,2048]

    // =============== P1: normalized adjacency ===============
    rowsum_rsqrt_k<<<NN, 256, 0, stream>>>(lr, r64, NN);
    build_A_k<<<(NN*NN + 255)/256, 256, 0, stream>>>(lr, r64, A32, A64, NN);

    // =============== P2: graph U-Net (fp32) ===============
    gemmf32(stream, EPI_BIAS, A32, start_w, out_start, NN, DIMF, NN, start_b, nullptr);

    const float* Xcur = out_start;
    const float* Acur = A32;
    float* ping = XP1; float* pong = XP2;
    for (int l = 0; l < 4; ++l){
        int nl = LVL_N[l], kl = LVL_K[l];
        gemmf32(stream, EPI_NONE, Acur, Xcur, XT, nl, DIMF, nl, nullptr, nullptr);
        gemmf32(stream, EPI_BIAS, XT, down_w + (size_t)l*DIMF*DIMF, DN[l], nl, DIMF, DIMF,
                down_b + (size_t)l*DIMF, nullptr);
        score_k<<<(nl + 3)/4, 256, 0, stream>>>(DN[l], pool_w + (size_t)l*DIMF, pool_b + l, SC, nl, DIMF);
        topk_k<<<1, 256, 0, stream>>>(SC, nl, kl, IDX[l], VAL[l]);
        gatherX_k<<<(unsigned)(((size_t)kl*DIMF + 255)/256), 256, 0, stream>>>(DN[l], IDX[l], VAL[l], ping, kl, DIMF);
        gatherA_k<<<(unsigned)(((size_t)kl*kl + 255)/256), 256, 0, stream>>>(Acur, IDX[l], Asub[l], kl, nl);
        Xcur = ping; Acur = Asub[l];
        float* t = ping; ping = pong; pong = t;
    }
    gemmf32(stream, EPI_NONE, Acur, Xcur, XT, 193, DIMF, 193, nullptr, nullptr);
    float* Xb = ping;
    gemmf32(stream, EPI_BIAS, XT, bottom_w, Xb, 193, DIMF, DIMF, bottom_b, nullptr);
    const float* Xup = Xb;
    float* upbuf[2] = { (Xb == XP1) ? XP2 : XP1, (Xb == XP1) ? XP1 : XP2 };
    for (int i2 = 0; i2 < 4; ++i2){
        int jl = 3 - i2;
        int nj = LVL_N[jl];
        int kj = LVL_K[jl];
        fill0_k<<<(unsigned)(((size_t)nj*DIMF + 255)/256), 256, 0, stream>>>(XU, (size_t)nj*DIMF);
        scatterX_k<<<(unsigned)(((size_t)kj*DIMF + 255)/256), 256, 0, stream>>>(Xup, IDX[jl], XU, kj, DIMF);
        const float* Aj = (jl == 0) ? A32 : Asub[jl - 1];
        gemmf32(stream, EPI_NONE, Aj, XU, XT, nj, DIMF, nj, nullptr, nullptr);
        float* Xn = upbuf[i2 & 1];
        gemmf32(stream, EPI_BIAS_ADD, XT, up_w + (size_t)i2*DIMF*DIMF, Xn, nj, DIMF, DIMF,
                up_b + (size_t)i2*DIMF, DN[jl]);
        Xup = Xn;
    }
    concat_k<<<(unsigned)(((size_t)NN*2*DIMF + 255)/256), 256, 0, stream>>>(Xup, out_start, XC, NN, DIMF);
    gemmf32(stream, EPI_NONE, A32, XC, AXC, NN, 2*DIMF, NN, nullptr, nullptr);
    gemmf32(stream, EPI_BIAS, AXC, end_w, out_net, NN, HRD, 2*DIMF, end_b, nullptr);

    // =============== P3: eigendecomposition of A (fp64) ===============
    filld0_k<<<4, 256, 0, stream>>>(pvA, NN);
    for (int j = 0; j < NN - TB; ++j){
        int m = NN - 1 - j;
        hh_fused_mv<<<(m + 3)/4, 256, 0, stream>>>(A64, dE, dTau, dScl, pbuf, pvA, NN, j);
        size_t tot = (size_t)m*m;
        hh_update2<<<(unsigned)((tot + 255)/256), 256, 0, stream>>>(A64, pbuf, pvA, dTau, dScl, NN, j);
    }
    hh_tail<<<1, 256, 0, stream>>>(A64, dE, dTau, dScl, NN);
    extract_de_k<<<4, 256, 0, stream>>>(A64, dD, dE, NN);
    bisect_k<<<4, 256, 0, stream>>>(dD, dE, dWev, NN);
    invit_k<<<4, 256, 0, stream>>>(dD, dE, dWev, FD, FL, FU, FU2, FPIV, Z64, NN);
    for (int g = 15; g >= 0; --g){
        int b0 = g*64;
        int nbsz = (NN - 2) - b0; if (nbsz > 64) nbsz = 64;
        build_V_k<<<(NN*64 + 255)/256, 256, 0, stream>>>(A64, dScl, Vp, NN, b0, nbsz);
        build_T_k<<<1, 256, 0, stream>>>(Vp, dTau, Tm, NN, b0, nbsz);
        int r0 = b0 + 1;
        gemmf64(stream, true,  Vp + (size_t)r0*64, 64, Z64 + (size_t)r0*NN, NN, Yt, NN, nbsz, NN, NN - r0, 1.0, 0.0);
        gemmf64(stream, false, Tm, 64, Yt, NN, W2, NN, nbsz, NN, nbsz, 1.0, 0.0);
        gemmf64(stream, false, Vp + (size_t)r0*64, 64, W2, NN, Z64 + (size_t)r0*NN, NN, NN - r0, NN, nbsz, -1.0, 1.0);
    }
    // U^T (cast + transpose): UfT[k][j] = U[j][k]
    {
        dim3 g(NN/32, NN/32), b(256);
        transpose_cast_k<<<g, b, 0, stream>>>(Z64, UfT, NN);
    }

    // =============== P4: GSR layer + refinement (fp32) ===============
    build_a_k<<<(unsigned)(((size_t)HRD*NN + 255)/256), 256, 0, stream>>>(gsr_w, P4a);
    gemmf32(stream, EPI_NONE, P4a, UfT, P4t1, HRD, NN, NN, nullptr, nullptr);               // a @ U^T
    gemmf32(stream, EPI_ABS_DIAG1, P4t1, out_net, out_adj, HRD, HRD, NN, nullptr, nullptr); // adj
    {
        dim3 g(HRD/32, HRD/32), b(256);
        transpose32_k<<<g, b, 0, stream>>>(out_adj, P4adT, HRD);                            // adj^T
    }
    gemmf32(stream, EPI_NONE, out_adj, P4adT, P4Zb, HRD, HRD, HRD, nullptr, nullptr);       // adj @ adj^T
    symabs1_k<<<(unsigned)(((size_t)HRD*HRD + 255)/256), 256, 0, stream>>>(P4Zb, HRD);      // Z
    gemmf32(stream, EPI_NONE, P4Zb, gc1, P4ZG, HRD, NN, HRD, nullptr, nullptr);             // Z @ gc1
    gemmf32(stream, EPI_RELU, out_adj, P4ZG, P4h1, HRD, NN, HRD, nullptr, nullptr);         // h1
    gemmf32(stream, EPI_NONE, P4h1, gc2, P4HG, HRD, HRD, NN, nullptr, nullptr);             // h1 @ gc2
    gemmf32(stream, EPI_RELU, out_adj, P4HG, P4h2, HRD, HRD, HRD, nullptr, nullptr);        // h2
    final_z_k<<<(unsigned)(((size_t)HRD*HRD + 255)/256), 256, 0, stream>>>(P4h2, out_z, HRD); // z
}